// Round 12
// baseline (419.203 us; speedup 1.0000x reference)
//
#include <hip/hip_runtime.h>
#include <stdint.h>

#define NTHREADS 256
#define KTOP 50
#define CAP 1024
#define SEGCAP 512
#define NSEG 4
#define EPSV 1e-8f

typedef unsigned long long u64;
typedef uint32_t u32;
typedef float __attribute__((ext_vector_type(4))) f4;

// s_c: 0=cntP 1=cntQ 2=ovfl 3=fallback counter
#define C_CNTP 0
#define C_CNTQ 1
#define C_OVF  2
#define C_GEN  3

// ---- block-wide float max ----
__device__ __forceinline__ float block_max(float v, float* s_f, int tid) {
    for (int off = 32; off; off >>= 1) v = fmaxf(v, __shfl_down(v, off));
    if ((tid & 63) == 0) s_f[tid >> 6] = v;
    __syncthreads();
    if (tid == 0) {
        float m = s_f[0];
        for (int w = 1; w < NTHREADS / 64; ++w) m = fmaxf(m, s_f[w]);
        s_f[4] = m;
    }
    __syncthreads();
    float r = s_f[4];
    __syncthreads();
    return r;
}

// ---- u32-key push (works on LDS or global pointers) ----
__device__ __forceinline__ void push32(u32* cand, u32* cnt, u32* ovf,
                                       float v, int idx, float t, u32 tbits,
                                       u32 cap) {
    if (v >= t) {
        u32 delta = __float_as_uint(v) - tbits;
        if (delta > 0xFFFFu) { *ovf = 1u; delta = 0xFFFFu; }
        u32 pos = atomicAdd(cnt, 1u);
        if (pos < cap) cand[pos] = (delta << 16) | (0xFFFFu - (u32)idx);
    }
}

// ---- u64 push (validated fallback path) ----
__device__ __forceinline__ void push64(u64* cand, u32* cnt,
                                       float v, int idx, float t) {
    if (v >= t) {
        u32 pos = atomicAdd(cnt, 1u);
        if (pos < CAP)
            cand[pos] = (((u64)__float_as_uint(v)) << 16) |
                        (u64)(0xFFFFu - (u32)idx);
    }
}

// ---- cold path: per-element direct u64 collect (validated R2-R11) ----
__device__ int collect_direct64(const float* __restrict__ row, int V, float t,
                                u64* cand, u32* s_cnt, int tid) {
    if (tid == 0) *s_cnt = 0;
    __syncthreads();
    int mis = (int)(((uintptr_t)row >> 2) & 3);
    int head = (4 - mis) & 3; if (head > V) head = V;
    if (tid < head) push64(cand, s_cnt, row[tid], tid, t);
    int nvec = (V - head) >> 2;
    const float4* vr = reinterpret_cast<const float4*>(row + head);
    for (int i = tid; i < nvec; i += NTHREADS) {
        float4 v = vr[i];
        int b = head + (i << 2);
        push64(cand, s_cnt, v.x, b, t);     push64(cand, s_cnt, v.y, b + 1, t);
        push64(cand, s_cnt, v.z, b + 2, t); push64(cand, s_cnt, v.w, b + 3, t);
    }
    for (int i = head + (nvec << 2) + tid; i < V; i += NTHREADS)
        push64(cand, s_cnt, row[i], i, t);
    __syncthreads();
    int n = (int)*s_cnt;
    __syncthreads();
    return n;
}

// ---- u64 two-phase find_topk (validated fallback) ----
__device__ void find_topk64(const u64* cand, int nc, uint16_t* top,
                            u64* s_merge, int tid) {
    int lane = tid & 63, w = tid >> 6;
    u64 r0 = 0, r1 = 0, r2 = 0, r3 = 0;
    int j0 = (w << 6) + lane;
    if (j0 < nc)       r0 = cand[j0];
    if (j0 + 256 < nc) r1 = cand[j0 + 256];
    if (j0 + 512 < nc) r2 = cand[j0 + 512];
    if (j0 + 768 < nc) r3 = cand[j0 + 768];
    for (int k = 0; k < KTOP; ++k) {
        u64 a = r0 > r1 ? r0 : r1;
        u64 b = r2 > r3 ? r2 : r3;
        u64 m = a > b ? a : b;
        #pragma unroll
        for (int off = 32; off; off >>= 1) {
            u64 o = __shfl_xor(m, off);
            if (o > m) m = o;
        }
        if (lane == 0) s_merge[w * KTOP + k] = m;
        if (r0 == m) r0 = 0; else if (r1 == m) r1 = 0;
        else if (r2 == m) r2 = 0; else if (r3 == m) r3 = 0;
    }
    __syncthreads();
    if (w == 0) {
        u64 q0 = 0, q1 = 0, q2 = 0, q3 = 0;
        if (lane < 4 * KTOP)       q0 = s_merge[lane];
        if (lane + 64 < 4 * KTOP)  q1 = s_merge[lane + 64];
        if (lane + 128 < 4 * KTOP) q2 = s_merge[lane + 128];
        if (lane + 192 < 4 * KTOP) q3 = s_merge[lane + 192];
        for (int k = 0; k < KTOP; ++k) {
            u64 a = q0 > q1 ? q0 : q1;
            u64 b = q2 > q3 ? q2 : q3;
            u64 m = a > b ? a : b;
            #pragma unroll
            for (int off = 32; off; off >>= 1) {
                u64 o = __shfl_xor(m, off);
                if (o > m) m = o;
            }
            if (lane == 0) top[k] = (uint16_t)(0xFFFFu - (u32)(m & 0xFFFFu));
            if (q0 == m) q0 = 0; else if (q1 == m) q1 = 0;
            else if (q2 == m) q2 = 0; else if (q3 == m) q3 = 0;
        }
    }
    __syncthreads();
}

// ---- single-wave u32 top-50 (LDS or global source) ----
template <int NR>
__device__ void find32(const u32* cand, int nc, uint16_t* top, int lane) {
    u32 r[NR];
    #pragma unroll
    for (int j = 0; j < NR; ++j) {
        int idx = lane + j * 64;
        r[j] = (idx < nc) ? cand[idx] : 0u;
    }
    u32 mine = 0;
    for (int k = 0; k < KTOP; ++k) {
        u32 m = 0;
        #pragma unroll
        for (int j = 0; j < NR; ++j) m = r[j] > m ? r[j] : m;
        #pragma unroll
        for (int off = 32; off; off >>= 1) {
            u32 o = __shfl_xor(m, off);
            m = o > m ? o : m;
        }
        if (lane == k) mine = m;
        #pragma unroll
        for (int j = 0; j < NR; ++j) if (r[j] == m) r[j] = 0;
    }
    if (lane < KTOP) top[lane] = (uint16_t)(0xFFFFu - (mine & 0xFFFFu));
}

// ---- inline-asm single load + counted wait (validated R9-R11) ----
#define ISSUE1(R, PTR) \
    asm volatile("global_load_dwordx4 %0, %1, off" \
                 : "=&v"(R) : "v"(PTR))

#define WAITV(N) do { \
    asm volatile("s_waitcnt vmcnt(" #N ")" ::: "memory"); \
    __builtin_amdgcn_sched_barrier(0); } while (0)

// ---- generic 6-slot pipelined stream over f4 range [lo,hi) ----
template <typename CB>
__device__ __forceinline__ void stream_range(const f4* __restrict__ v4,
                                             int lo, int hi, int tid, CB&& cb) {
    int len = hi - lo;
    int ngrp = len / NTHREADS;
    int ring = 0;
    if (ngrp >= 12) {
        f4 s0, s1, s2, s3, s4, s5;
        const f4* pp = v4 + lo + tid;
        ISSUE1(s0, pp); pp += NTHREADS;
        ISSUE1(s1, pp); pp += NTHREADS;
        ISSUE1(s2, pp); pp += NTHREADS;
        ISSUE1(s3, pp); pp += NTHREADS;
        ISSUE1(s4, pp); pp += NTHREADS;
        ISSUE1(s5, pp); pp += NTHREADS;
        int gend6 = ((ngrp - 6) / 6) * 6;
        int g = 0;
        for (; g < gend6; g += 6) {
            WAITV(5); cb(s0, lo + (g + 0) * NTHREADS + tid); ISSUE1(s0, pp); pp += NTHREADS;
            WAITV(5); cb(s1, lo + (g + 1) * NTHREADS + tid); ISSUE1(s1, pp); pp += NTHREADS;
            WAITV(5); cb(s2, lo + (g + 2) * NTHREADS + tid); ISSUE1(s2, pp); pp += NTHREADS;
            WAITV(5); cb(s3, lo + (g + 3) * NTHREADS + tid); ISSUE1(s3, pp); pp += NTHREADS;
            WAITV(5); cb(s4, lo + (g + 4) * NTHREADS + tid); ISSUE1(s4, pp); pp += NTHREADS;
            WAITV(5); cb(s5, lo + (g + 5) * NTHREADS + tid); ISSUE1(s5, pp); pp += NTHREADS;
        }
        WAITV(0);
        cb(s0, lo + (g + 0) * NTHREADS + tid);
        cb(s1, lo + (g + 1) * NTHREADS + tid);
        cb(s2, lo + (g + 2) * NTHREADS + tid);
        cb(s3, lo + (g + 3) * NTHREADS + tid);
        cb(s4, lo + (g + 4) * NTHREADS + tid);
        cb(s5, lo + (g + 5) * NTHREADS + tid);
        ring = g + 6;
    }
    for (int i = lo + ring * NTHREADS + tid; i < hi; i += NTHREADS)
        cb(v4[i], i);
}

// ---- shared union+sums+JSD epilogue (validated) ----
__device__ void jsd_epilogue(const float* __restrict__ prow,
                             const float* __restrict__ qrow, int V,
                             const uint16_t* topP, const uint16_t* topQ,
                             uint16_t* s_union, int* s_nu, float* s_f,
                             float* __restrict__ out, int row, int tid) {
    int w = tid >> 6;
    if (tid < KTOP) s_union[tid] = topP[tid];
    __syncthreads();
    if (tid < 64) {
        bool freshb = false; uint16_t qi = 0;
        if (tid < KTOP) {
            qi = topQ[tid]; freshb = true;
            for (int j = 0; j < KTOP; ++j) if (topP[j] == qi) freshb = false;
        }
        u64 mb = __ballot(freshb);
        int pos = __popcll(mb & ((1ull << tid) - 1ull));
        if (freshb) s_union[KTOP + pos] = qi;
        if (tid == 0) *s_nu = KTOP + __popcll(mb);
    }
    __syncthreads();
    int nu = *s_nu;

    float pv = 0.f, qv = 0.f;
    if (tid < nu) {
        int ui = s_union[tid]; ui = ui < V ? ui : V - 1;
        pv = prow[ui];
        qv = qrow[ui];
    }
    float sp = pv, sq = qv;
    for (int off = 32; off; off >>= 1) { sp += __shfl_down(sp, off); sq += __shfl_down(sq, off); }
    if ((tid & 63) == 0) { s_f[w] = sp; s_f[4 + w] = sq; }
    __syncthreads();
    if (tid == 0) {
        float a = 0.f, b = 0.f;
        for (int ww = 0; ww < NTHREADS / 64; ++ww) { a += s_f[ww]; b += s_f[4 + ww]; }
        s_f[0] = a; s_f[4] = b;
    }
    __syncthreads();
    float sump = s_f[0], sumq = s_f[4];
    __syncthreads();

    float term = 0.f;
    if (tid < nu) {
        float pn = pv / (sump + EPSV);
        float qn = qv / (sumq + EPSV);
        float mn = 0.5f * (pn + qn);
        float ps = pn + EPSV, qs = qn + EPSV, ms = mn + EPSV;
        term = 0.5f * (ps * logf(ps / ms) + qs * logf(qs / ms));
    }
    for (int off = 32; off; off >>= 1) term += __shfl_down(term, off);
    if ((tid & 63) == 0) s_f[w] = term;
    __syncthreads();
    if (tid == 0) {
        float a = 0.f;
        for (int ww = 0; ww < NTHREADS / 64; ++ww) a += s_f[ww];
        out[row] = a;
    }
}

// ================= phase 0: per-(row,array) threshold =================
__global__ __launch_bounds__(NTHREADS)
void thresh_kernel(const float* __restrict__ p, const float* __restrict__ q,
                   u32* __restrict__ cnt, u32* __restrict__ ovfw,
                   float* __restrict__ msarr, u32* __restrict__ tb, int V)
{
    __shared__ float s_f[8];
    int row = blockIdx.x, tid = threadIdx.x;
    const float* prow = p + (size_t)row * (size_t)V;
    const float* qrow = q + (size_t)row * (size_t)V;
    int smp = V < 2048 ? V : 2048;
    float msP = 0.f, msQ = 0.f;
    for (int i = tid; i < smp; i += NTHREADS) {
        msP = fmaxf(msP, prow[i]);
        msQ = fmaxf(msQ, qrow[i]);
    }
    float MsP = block_max(msP, s_f, tid);
    float MsQ = block_max(msQ, s_f, tid);
    float eps0 = fminf(128.f / (float)V + 1.f / (float)smp, 0.5f);
    if (tid == 0) {
        msarr[2 * row]     = MsP;
        msarr[2 * row + 1] = MsQ;
        tb[2 * row]     = __float_as_uint(MsP * (1.f - eps0));
        tb[2 * row + 1] = __float_as_uint(MsQ * (1.f - eps0));
        cnt[2 * row] = 0;  cnt[2 * row + 1] = 0;
        ovfw[2 * row] = 0; ovfw[2 * row + 1] = 0;
    }
}

// ================= phase 1: pure streaming collect (fillBuffer-shaped) =====
__global__ __launch_bounds__(NTHREADS, 8)
void stream_kernel(const float* __restrict__ p, const float* __restrict__ q,
                   u32* __restrict__ cnt, u32* __restrict__ ovfw,
                   const u32* __restrict__ tb, u32* __restrict__ cands, int V)
{
    __shared__ u32 candL[SEGCAP];
    __shared__ u32 s_nL;
    __shared__ u32 s_base;

    int bid = blockIdx.x;
    int row   = bid >> 3;            // / (2*NSEG) with NSEG=4
    int r     = bid & 7;
    int which = r >> 2;
    int seg   = r & 3;
    int tid = threadIdx.x;

    const float* rw = (which ? q : p) + (size_t)row * (size_t)V;
    int slot = 2 * row + which;
    u32 tbits = tb[slot];
    float t = __uint_as_float(tbits);
    u32* gcand = cands + (size_t)slot * CAP;

    if (tid == 0) s_nL = 0;
    __syncthreads();

    int mis = (int)(((uintptr_t)rw >> 2) & 3);
    int head = (4 - mis) & 3; if (head > V) head = V;
    int nvec = (V - head) >> 2;
    int lo = (int)(((long long)nvec * seg) / NSEG);
    int hi = (int)(((long long)nvec * (seg + 1)) / NSEG);
    const f4* v4 = reinterpret_cast<const f4*>(rw + head);

    auto pushL = [&](float v, int idx) {
        if (v >= t) {
            u32 delta = __float_as_uint(v) - tbits;
            if (delta > 0xFFFFu) { ovfw[slot] = 1u; delta = 0xFFFFu; }
            u32 pos = atomicAdd(&s_nL, 1u);
            if (pos < SEGCAP) candL[pos] = (delta << 16) | (0xFFFFu - (u32)idx);
        }
    };

    if (seg == 0 && tid < head) pushL(rw[tid], tid);

    stream_range(v4, lo, hi, tid, [&](f4 v, int fi) {
        float m = fmaxf(fmaxf(v.x, v.y), fmaxf(v.z, v.w));
        if (m >= t) {
            int e = head + (fi << 2);
            pushL(v.x, e); pushL(v.y, e + 1); pushL(v.z, e + 2); pushL(v.w, e + 3);
        }
    });

    if (seg == NSEG - 1)
        for (int i = head + (nvec << 2) + tid; i < V; i += NTHREADS)
            pushL(rw[i], i);

    __syncthreads();
    u32 nL = s_nL;
    if (nL > SEGCAP) {                 // lost candidates -> force fallback
        if (tid == 0) { ovfw[slot] = 1u; atomicAdd(&cnt[slot], nL); }
        return;
    }
    if (tid == 0) s_base = nL ? atomicAdd(&cnt[slot], nL) : 0u;
    __syncthreads();
    u32 base = s_base;
    for (u32 i = tid; i < nL; i += NTHREADS) {
        u32 d = base + i;
        if (d < CAP) gcand[d] = candL[i];  // d>=CAP dropped; cnt>CAP flags fallback
    }
}

// ================= phase 2: select + union + JSD =================
__global__ __launch_bounds__(NTHREADS)
void finish_kernel(const float* __restrict__ p, const float* __restrict__ q,
                   const u32* __restrict__ cnt, const u32* __restrict__ ovfw,
                   const float* __restrict__ msarr, const u32* __restrict__ cands,
                   float* __restrict__ out, int V)
{
    __shared__ u64 candRaw[CAP];
    __shared__ u64 s_merge[4 * KTOP];
    __shared__ float s_f[8];
    __shared__ u32 s_c[4];
    __shared__ uint16_t topP[KTOP];
    __shared__ uint16_t topQ[KTOP];
    __shared__ uint16_t s_union[2 * KTOP];
    __shared__ int s_nu;

    int row = blockIdx.x, tid = threadIdx.x;
    int lane = tid & 63, w = tid >> 6;
    const float* prow = p + (size_t)row * (size_t)V;
    const float* qrow = q + (size_t)row * (size_t)V;

    int ncP = (int)cnt[2 * row], ncQ = (int)cnt[2 * row + 1];
    u32 ovP = ovfw[2 * row], ovQ = ovfw[2 * row + 1];
    bool okP = !ovP && ncP >= KTOP && ncP <= CAP;
    bool okQ = !ovQ && ncQ >= KTOP && ncQ <= CAP;

    if (okP && w == 0) {
        const u32* cp = cands + (size_t)(2 * row) * CAP;
        if (ncP <= 256) find32<4>(cp, ncP, topP, lane);
        else            find32<16>(cp, ncP, topP, lane);
    }
    if (okQ && w == 1) {
        const u32* cq = cands + (size_t)(2 * row + 1) * CAP;
        if (ncQ <= 256) find32<4>(cq, ncQ, topQ, lane);
        else            find32<16>(cq, ncQ, topQ, lane);
    }

    int smp = V < 2048 ? V : 2048;
    float eps0 = fminf(128.f / (float)V + 1.f / (float)smp, 0.5f);

    if (!okP) {
        float Ms = msarr[2 * row];
        float eps = eps0;
        int nc = collect_direct64(prow, V, Ms * (1.f - eps), candRaw, &s_c[C_GEN], tid);
        for (int a = 0; a < 10 && (nc < KTOP || nc > CAP); ++a) {
            eps = (nc > CAP) ? eps * 0.25f : fminf(eps * 4.f, 1.f);
            nc = collect_direct64(prow, V, Ms * (1.f - eps), candRaw, &s_c[C_GEN], tid);
        }
        if (nc > CAP) nc = CAP;
        find_topk64(candRaw, nc, topP, s_merge, tid);
    }
    if (!okQ) {
        float Ms = msarr[2 * row + 1];
        float eps = eps0;
        int nc = collect_direct64(qrow, V, Ms * (1.f - eps), candRaw, &s_c[C_GEN], tid);
        for (int a = 0; a < 10 && (nc < KTOP || nc > CAP); ++a) {
            eps = (nc > CAP) ? eps * 0.25f : fminf(eps * 4.f, 1.f);
            nc = collect_direct64(qrow, V, Ms * (1.f - eps), candRaw, &s_c[C_GEN], tid);
        }
        if (nc > CAP) nc = CAP;
        find_topk64(candRaw, nc, topQ, s_merge, tid);
    }
    __syncthreads();

    jsd_epilogue(prow, qrow, V, topP, topQ, s_union, &s_nu, s_f, out, row, tid);
}

// ============ validated single-kernel path (R11) for small ws ============
__global__ __launch_bounds__(NTHREADS, 8)
void topk_jsd_kernel(const float* __restrict__ p, const float* __restrict__ q,
                     float* __restrict__ out, int V)
{
    __shared__ u64 candRaw[CAP];
    __shared__ u64 s_merge[4 * KTOP];
    __shared__ float s_f[8];
    __shared__ u32 s_c[4];
    __shared__ uint16_t topP[KTOP];
    __shared__ uint16_t topQ[KTOP];
    __shared__ uint16_t s_union[2 * KTOP];
    __shared__ int s_nu;

    u32* candP = (u32*)candRaw;
    u32* candQ = ((u32*)candRaw) + CAP;

    const int row = blockIdx.x;
    const int tid = threadIdx.x;
    const int lane = tid & 63, w = tid >> 6;
    const float* prow = p + (size_t)row * (size_t)V;
    const float* qrow = q + (size_t)row * (size_t)V;

    int smp = V < 2048 ? V : 2048;
    float msP = 0.f, msQ = 0.f;
    for (int i = tid; i < smp; i += NTHREADS) {
        msP = fmaxf(msP, prow[i]);
        msQ = fmaxf(msQ, qrow[i]);
    }
    float MsP = block_max(msP, s_f, tid);
    float MsQ = block_max(msQ, s_f, tid);

    float eps0 = fminf(128.f / (float)V + 1.f / (float)smp, 0.5f);
    float tP = MsP * (1.f - eps0);
    float tQ = MsQ * (1.f - eps0);
    u32 tPb = __float_as_uint(tP), tQb = __float_as_uint(tQ);

    if (tid == 0) { s_c[0] = 0; s_c[1] = 0; s_c[2] = 0; }
    __syncthreads();

    {
        int mis = (int)(((uintptr_t)prow >> 2) & 3);
        int head = (4 - mis) & 3; if (head > V) head = V;
        int nvec = (V - head) >> 2;
        const f4* v4 = reinterpret_cast<const f4*>(prow + head);
        if (tid < head) push32(candP, &s_c[C_CNTP], &s_c[C_OVF], prow[tid], tid, tP, tPb, CAP);
        stream_range(v4, 0, nvec, tid, [&](f4 v, int fi) {
            float m = fmaxf(fmaxf(v.x, v.y), fmaxf(v.z, v.w));
            if (m >= tP) {
                int e = head + (fi << 2);
                push32(candP, &s_c[C_CNTP], &s_c[C_OVF], v.x, e,     tP, tPb, CAP);
                push32(candP, &s_c[C_CNTP], &s_c[C_OVF], v.y, e + 1, tP, tPb, CAP);
                push32(candP, &s_c[C_CNTP], &s_c[C_OVF], v.z, e + 2, tP, tPb, CAP);
                push32(candP, &s_c[C_CNTP], &s_c[C_OVF], v.w, e + 3, tP, tPb, CAP);
            }
        });
        for (int i = head + (nvec << 2) + tid; i < V; i += NTHREADS)
            push32(candP, &s_c[C_CNTP], &s_c[C_OVF], prow[i], i, tP, tPb, CAP);
    }
    {
        int mis = (int)(((uintptr_t)qrow >> 2) & 3);
        int head = (4 - mis) & 3; if (head > V) head = V;
        int nvec = (V - head) >> 2;
        const f4* v4 = reinterpret_cast<const f4*>(qrow + head);
        if (tid < head) push32(candQ, &s_c[C_CNTQ], &s_c[C_OVF], qrow[tid], tid, tQ, tQb, CAP);
        stream_range(v4, 0, nvec, tid, [&](f4 v, int fi) {
            float m = fmaxf(fmaxf(v.x, v.y), fmaxf(v.z, v.w));
            if (m >= tQ) {
                int e = head + (fi << 2);
                push32(candQ, &s_c[C_CNTQ], &s_c[C_OVF], v.x, e,     tQ, tQb, CAP);
                push32(candQ, &s_c[C_CNTQ], &s_c[C_OVF], v.y, e + 1, tQ, tQb, CAP);
                push32(candQ, &s_c[C_CNTQ], &s_c[C_OVF], v.z, e + 2, tQ, tQb, CAP);
                push32(candQ, &s_c[C_CNTQ], &s_c[C_OVF], v.w, e + 3, tQ, tQb, CAP);
            }
        });
        for (int i = head + (nvec << 2) + tid; i < V; i += NTHREADS)
            push32(candQ, &s_c[C_CNTQ], &s_c[C_OVF], qrow[i], i, tQ, tQb, CAP);
    }

    __syncthreads();
    int ncP = (int)s_c[C_CNTP];
    int ncQ = (int)s_c[C_CNTQ];
    u32 ovf = s_c[C_OVF];
    __syncthreads();

    bool okP = !ovf && ncP >= KTOP && ncP <= CAP;
    bool okQ = !ovf && ncQ >= KTOP && ncQ <= CAP;

    if (okP && w == 0) {
        if (ncP <= 256) find32<4>(candP, ncP, topP, lane);
        else            find32<16>(candP, ncP, topP, lane);
    }
    if (okQ && w == 1) {
        if (ncQ <= 256) find32<4>(candQ, ncQ, topQ, lane);
        else            find32<16>(candQ, ncQ, topQ, lane);
    }

    if (!okP) {
        float eps = eps0;
        int nc = collect_direct64(prow, V, MsP * (1.f - eps), candRaw, &s_c[C_GEN], tid);
        for (int a = 0; a < 10 && (nc < KTOP || nc > CAP); ++a) {
            eps = (nc > CAP) ? eps * 0.25f : fminf(eps * 4.f, 1.f);
            nc = collect_direct64(prow, V, MsP * (1.f - eps), candRaw, &s_c[C_GEN], tid);
        }
        if (nc > CAP) nc = CAP;
        find_topk64(candRaw, nc, topP, s_merge, tid);
    }
    if (!okQ) {
        float eps = eps0;
        int nc = collect_direct64(qrow, V, MsQ * (1.f - eps), candRaw, &s_c[C_GEN], tid);
        for (int a = 0; a < 10 && (nc < KTOP || nc > CAP); ++a) {
            eps = (nc > CAP) ? eps * 0.25f : fminf(eps * 4.f, 1.f);
            nc = collect_direct64(qrow, V, MsQ * (1.f - eps), candRaw, &s_c[C_GEN], tid);
        }
        if (nc > CAP) nc = CAP;
        find_topk64(candRaw, nc, topQ, s_merge, tid);
    }
    __syncthreads();

    jsd_epilogue(prow, qrow, V, topP, topQ, s_union, &s_nu, s_f, out, row, tid);
}

extern "C" void kernel_launch(void* const* d_in, const int* in_sizes, int n_in,
                              void* d_out, int out_size, void* d_ws, size_t ws_size,
                              hipStream_t stream) {
    const float* p = (const float*)d_in[0];
    const float* q = (const float*)d_in[1];
    float* out = (float*)d_out;
    if (out_size <= 0) return;
    int N = out_size;            // B*S rows
    int V = in_sizes[0] / N;     // vocab size
    size_t slots = (size_t)2 * N;
    size_t need = slots * 4 * sizeof(u32) + slots * CAP * sizeof(u32);
    if (d_ws && ws_size >= need && V >= 64) {
        u32* cnt    = (u32*)d_ws;
        u32* ovfw   = cnt + slots;
        float* msar = (float*)(ovfw + slots);
        u32* tb     = (u32*)(msar + slots);
        u32* cands  = tb + slots;
        thresh_kernel<<<dim3(N), dim3(NTHREADS), 0, stream>>>(p, q, cnt, ovfw, msar, tb, V);
        stream_kernel<<<dim3(N * 2 * NSEG), dim3(NTHREADS), 0, stream>>>(p, q, cnt, ovfw, tb, cands, V);
        finish_kernel<<<dim3(N), dim3(NTHREADS), 0, stream>>>(p, q, cnt, ovfw, msar, cands, out, V);
    } else {
        topk_jsd_kernel<<<dim3(N), dim3(NTHREADS), 0, stream>>>(p, q, out, V);
    }
}

// Round 13
// 386.865 us; speedup vs baseline: 1.0836x; 1.0836x over previous
//
#include <hip/hip_runtime.h>
#include <stdint.h>

#define NTHREADS 256
#define KTOP 50
#define CAP 1024
#define EPSV 1e-8f

typedef unsigned long long u64;
typedef uint32_t u32;
typedef float __attribute__((ext_vector_type(4))) f4;

// s_c: 0=cntP 1=cntQ 2=ovfl 3=fallback counter
#define C_CNTP 0
#define C_CNTQ 1
#define C_OVF  2
#define C_GEN  3

// ---- block-wide float max ----
__device__ __forceinline__ float block_max(float v, float* s_f, int tid) {
    for (int off = 32; off; off >>= 1) v = fmaxf(v, __shfl_down(v, off));
    if ((tid & 63) == 0) s_f[tid >> 6] = v;
    __syncthreads();
    if (tid == 0) {
        float m = s_f[0];
        for (int w = 1; w < NTHREADS / 64; ++w) m = fmaxf(m, s_f[w]);
        s_f[4] = m;
    }
    __syncthreads();
    float r = s_f[4];
    __syncthreads();
    return r;
}

// ---- u32-key push: key = (bits(v)-bits(t))<<16 | (0xFFFF-idx) ----
__device__ __forceinline__ void push32(u32* cand, u32* cnt, u32* ovf,
                                       float v, int idx, float t, u32 tbits) {
    if (v >= t) {
        u32 delta = __float_as_uint(v) - tbits;
        if (delta > 0xFFFFu) { *ovf = 1u; delta = 0xFFFFu; }
        u32 pos = atomicAdd(cnt, 1u);
        if (pos < CAP) cand[pos] = (delta << 16) | (0xFFFFu - (u32)idx);
    }
}

// ---- u64 push (validated fallback path) ----
__device__ __forceinline__ void push64(u64* cand, u32* cnt,
                                       float v, int idx, float t) {
    if (v >= t) {
        u32 pos = atomicAdd(cnt, 1u);
        if (pos < CAP)
            cand[pos] = (((u64)__float_as_uint(v)) << 16) |
                        (u64)(0xFFFFu - (u32)idx);
    }
}

// ---- cold path: per-element direct u64 collect (validated R2-R12) ----
__device__ int collect_direct64(const float* __restrict__ row, int V, float t,
                                u64* cand, u32* s_cnt, int tid) {
    if (tid == 0) *s_cnt = 0;
    __syncthreads();
    int mis = (int)(((uintptr_t)row >> 2) & 3);
    int head = (4 - mis) & 3; if (head > V) head = V;
    if (tid < head) push64(cand, s_cnt, row[tid], tid, t);
    int nvec = (V - head) >> 2;
    const float4* vr = reinterpret_cast<const float4*>(row + head);
    for (int i = tid; i < nvec; i += NTHREADS) {
        float4 v = vr[i];
        int b = head + (i << 2);
        push64(cand, s_cnt, v.x, b, t);     push64(cand, s_cnt, v.y, b + 1, t);
        push64(cand, s_cnt, v.z, b + 2, t); push64(cand, s_cnt, v.w, b + 3, t);
    }
    for (int i = head + (nvec << 2) + tid; i < V; i += NTHREADS)
        push64(cand, s_cnt, row[i], i, t);
    __syncthreads();
    int n = (int)*s_cnt;
    __syncthreads();
    return n;
}

// ---- u64 two-phase find_topk (validated fallback) ----
__device__ void find_topk64(const u64* cand, int nc, uint16_t* top,
                            u64* s_merge, int tid) {
    int lane = tid & 63, w = tid >> 6;
    u64 r0 = 0, r1 = 0, r2 = 0, r3 = 0;
    int j0 = (w << 6) + lane;
    if (j0 < nc)       r0 = cand[j0];
    if (j0 + 256 < nc) r1 = cand[j0 + 256];
    if (j0 + 512 < nc) r2 = cand[j0 + 512];
    if (j0 + 768 < nc) r3 = cand[j0 + 768];
    for (int k = 0; k < KTOP; ++k) {
        u64 a = r0 > r1 ? r0 : r1;
        u64 b = r2 > r3 ? r2 : r3;
        u64 m = a > b ? a : b;
        #pragma unroll
        for (int off = 32; off; off >>= 1) {
            u64 o = __shfl_xor(m, off);
            if (o > m) m = o;
        }
        if (lane == 0) s_merge[w * KTOP + k] = m;
        if (r0 == m) r0 = 0; else if (r1 == m) r1 = 0;
        else if (r2 == m) r2 = 0; else if (r3 == m) r3 = 0;
    }
    __syncthreads();
    if (w == 0) {
        u64 q0 = 0, q1 = 0, q2 = 0, q3 = 0;
        if (lane < 4 * KTOP)       q0 = s_merge[lane];
        if (lane + 64 < 4 * KTOP)  q1 = s_merge[lane + 64];
        if (lane + 128 < 4 * KTOP) q2 = s_merge[lane + 128];
        if (lane + 192 < 4 * KTOP) q3 = s_merge[lane + 192];
        for (int k = 0; k < KTOP; ++k) {
            u64 a = q0 > q1 ? q0 : q1;
            u64 b = q2 > q3 ? q2 : q3;
            u64 m = a > b ? a : b;
            #pragma unroll
            for (int off = 32; off; off >>= 1) {
                u64 o = __shfl_xor(m, off);
                if (o > m) m = o;
            }
            if (lane == 0) top[k] = (uint16_t)(0xFFFFu - (u32)(m & 0xFFFFu));
            if (q0 == m) q0 = 0; else if (q1 == m) q1 = 0;
            else if (q2 == m) q2 = 0; else if (q3 == m) q3 = 0;
        }
    }
    __syncthreads();
}

// ---- single-wave u32 top-50: zero barriers, non-destructive LDS reads ----
template <int NR>
__device__ void find32(const u32* cand, int nc, uint16_t* top, int lane) {
    u32 r[NR];
    #pragma unroll
    for (int j = 0; j < NR; ++j) {
        int idx = lane + j * 64;
        r[j] = (idx < nc) ? cand[idx] : 0u;
    }
    u32 mine = 0;
    for (int k = 0; k < KTOP; ++k) {
        u32 m = 0;
        #pragma unroll
        for (int j = 0; j < NR; ++j) m = r[j] > m ? r[j] : m;
        #pragma unroll
        for (int off = 32; off; off >>= 1) {
            u32 o = __shfl_xor(m, off);
            m = o > m ? o : m;
        }
        if (lane == k) mine = m;
        #pragma unroll
        for (int j = 0; j < NR; ++j) if (r[j] == m) r[j] = 0;
    }
    if (lane < KTOP) top[lane] = (uint16_t)(0xFFFFu - (mine & 0xFFFFu));
}

// ---- inline-asm load pair, NON-TEMPORAL: read-once stream bypasses LRU ----
#define ISSUE(RP, RQ, IDX) \
    asm volatile("global_load_dwordx4 %0, %2, off nt\n\t" \
                 "global_load_dwordx4 %1, %3, off nt" \
                 : "=&v"(RP), "=&v"(RQ) \
                 : "v"(vp4 + (IDX)), "v"(vq4 + (IDX)))

// counted wait: oldest pair complete, rest in flight; fence VALU hoisting
#define WAITV(N) do { \
    asm volatile("s_waitcnt vmcnt(" #N ")" ::: "memory"); \
    __builtin_amdgcn_sched_barrier(0); } while (0)

#define CONSUME(RP, RQ, G) do { \
    float _mp = fmaxf(fmaxf(RP.x, RP.y), fmaxf(RP.z, RP.w)); \
    float _mq = fmaxf(fmaxf(RQ.x, RQ.y), fmaxf(RQ.z, RQ.w)); \
    int _e = head + (((G) * NTHREADS + tid) << 2); \
    if (_mp >= tP) { \
        push32(candP, &s_c[C_CNTP], &s_c[C_OVF], RP.x, _e,     tP, tPb); \
        push32(candP, &s_c[C_CNTP], &s_c[C_OVF], RP.y, _e + 1, tP, tPb); \
        push32(candP, &s_c[C_CNTP], &s_c[C_OVF], RP.z, _e + 2, tP, tPb); \
        push32(candP, &s_c[C_CNTP], &s_c[C_OVF], RP.w, _e + 3, tP, tPb); \
    } \
    if (_mq >= tQ) { \
        push32(candQ, &s_c[C_CNTQ], &s_c[C_OVF], RQ.x, _e,     tQ, tQb); \
        push32(candQ, &s_c[C_CNTQ], &s_c[C_OVF], RQ.y, _e + 1, tQ, tQb); \
        push32(candQ, &s_c[C_CNTQ], &s_c[C_OVF], RQ.z, _e + 2, tQ, tQb); \
        push32(candQ, &s_c[C_CNTQ], &s_c[C_OVF], RQ.w, _e + 3, tQ, tQb); \
    } } while (0)

__global__ __launch_bounds__(NTHREADS, 4)
void topk_jsd_kernel(const float* __restrict__ p, const float* __restrict__ q,
                     float* __restrict__ out, int V)
{
    __shared__ u64 candRaw[CAP];                 // u32 views: P = lo 4KB, Q = hi 4KB
    __shared__ u64 s_merge[4 * KTOP];
    __shared__ float s_f[8];
    __shared__ u32 s_c[4];
    __shared__ uint16_t topP[KTOP];
    __shared__ uint16_t topQ[KTOP];
    __shared__ uint16_t s_union[2 * KTOP];
    __shared__ int s_nu;

    u32* candP = (u32*)candRaw;
    u32* candQ = ((u32*)candRaw) + CAP;

    const int row = blockIdx.x;
    const int tid = threadIdx.x;
    const int lane = tid & 63, w = tid >> 6;
    const float* prow = p + (size_t)row * (size_t)V;
    const float* qrow = q + (size_t)row * (size_t)V;

    // ---- sample phase: max of first 2048 elems ----
    int smp = V < 2048 ? V : 2048;
    float msP = 0.f, msQ = 0.f;
    for (int i = tid; i < smp; i += NTHREADS) {
        msP = fmaxf(msP, prow[i]);
        msQ = fmaxf(msQ, qrow[i]);
    }
    float MsP = block_max(msP, s_f, tid);
    float MsQ = block_max(msQ, s_f, tid);

    float eps0 = fminf(128.f / (float)V + 1.f / (float)smp, 0.5f);
    float tP = MsP * (1.f - eps0);
    float tQ = MsQ * (1.f - eps0);
    u32 tPb = __float_as_uint(tP), tQb = __float_as_uint(tQ);

    int misP = (int)(((uintptr_t)prow >> 2) & 3);
    int misQ = (int)(((uintptr_t)qrow >> 2) & 3);
    int headP = (4 - misP) & 3; if (headP > V) headP = V;
    int headQ = (4 - misQ) & 3; if (headQ > V) headQ = V;
    bool fast = (headP == headQ);

    int ncP = -1, ncQ = -1;
    u32 ovf = 1;

    if (fast) {
        int head = headP;
        if (tid == 0) { s_c[0] = 0; s_c[1] = 0; s_c[2] = 0; }
        __syncthreads();
        int nvec = (V - head) >> 2;
        const f4* vp4 = reinterpret_cast<const f4*>(prow + head);
        const f4* vq4 = reinterpret_cast<const f4*>(qrow + head);

        // head elements
        if (tid < head) {
            push32(candP, &s_c[C_CNTP], &s_c[C_OVF], prow[tid], tid, tP, tPb);
            push32(candQ, &s_c[C_CNTQ], &s_c[C_OVF], qrow[tid], tid, tQ, tQb);
        }

        // ---- inline-asm pipelined stream: 4-slot ring, 8 nt-loads in flight
        int n4 = (nvec / NTHREADS) & ~3;   // per-thread groups, multiple of 4
        if (n4 >= 8) {
            f4 p0, p1, p2, p3, q0, q1, q2, q3;
            ISSUE(p0, q0, 0 * NTHREADS + tid);
            ISSUE(p1, q1, 1 * NTHREADS + tid);
            ISSUE(p2, q2, 2 * NTHREADS + tid);
            ISSUE(p3, q3, 3 * NTHREADS + tid);
            int gend = n4 - 4;             // multiple of 4
            for (int g = 0; g < gend; g += 4) {
                WAITV(6); CONSUME(p0, q0, g + 0); ISSUE(p0, q0, (g + 4) * NTHREADS + tid);
                WAITV(6); CONSUME(p1, q1, g + 1); ISSUE(p1, q1, (g + 5) * NTHREADS + tid);
                WAITV(6); CONSUME(p2, q2, g + 2); ISSUE(p2, q2, (g + 6) * NTHREADS + tid);
                WAITV(6); CONSUME(p3, q3, g + 3); ISSUE(p3, q3, (g + 7) * NTHREADS + tid);
            }
            WAITV(0);
            CONSUME(p0, q0, gend + 0);
            CONSUME(p1, q1, gend + 1);
            CONSUME(p2, q2, gend + 2);
            CONSUME(p3, q3, gend + 3);
        } else {
            n4 = 0;
        }

        // remaining float4s + scalar tail (per-element, validated path)
        for (int i = n4 * NTHREADS + tid; i < nvec; i += NTHREADS) {
            f4 a = vp4[i], b = vq4[i];
            int e = head + (i << 2);
            push32(candP, &s_c[C_CNTP], &s_c[C_OVF], a.x, e,     tP, tPb);
            push32(candP, &s_c[C_CNTP], &s_c[C_OVF], a.y, e + 1, tP, tPb);
            push32(candP, &s_c[C_CNTP], &s_c[C_OVF], a.z, e + 2, tP, tPb);
            push32(candP, &s_c[C_CNTP], &s_c[C_OVF], a.w, e + 3, tP, tPb);
            push32(candQ, &s_c[C_CNTQ], &s_c[C_OVF], b.x, e,     tQ, tQb);
            push32(candQ, &s_c[C_CNTQ], &s_c[C_OVF], b.y, e + 1, tQ, tQb);
            push32(candQ, &s_c[C_CNTQ], &s_c[C_OVF], b.z, e + 2, tQ, tQb);
            push32(candQ, &s_c[C_CNTQ], &s_c[C_OVF], b.w, e + 3, tQ, tQb);
        }
        for (int i = head + (nvec << 2) + tid; i < V; i += NTHREADS) {
            push32(candP, &s_c[C_CNTP], &s_c[C_OVF], prow[i], i, tP, tPb);
            push32(candQ, &s_c[C_CNTQ], &s_c[C_OVF], qrow[i], i, tQ, tQb);
        }
        __syncthreads();
        ncP = (int)s_c[C_CNTP];
        ncQ = (int)s_c[C_CNTQ];
        ovf = s_c[C_OVF];
        __syncthreads();
    }

    bool okP = fast && !ovf && ncP >= KTOP && ncP <= CAP;
    bool okQ = fast && !ovf && ncQ >= KTOP && ncQ <= CAP;

    // parallel single-wave extraction (non-destructive reads of cand LDS)
    if (okP && w == 0) {
        if (ncP <= 256) find32<4>(candP, ncP, topP, lane);
        else            find32<16>(candP, ncP, topP, lane);
    }
    if (okQ && w == 1) {
        if (ncQ <= 256) find32<4>(candQ, ncQ, topQ, lane);
        else            find32<16>(candQ, ncQ, topQ, lane);
    }

    // u64 fallback (validated path; overwrites candRaw)
    if (!okP) {
        float eps = eps0;
        int nc = collect_direct64(prow, V, MsP * (1.f - eps), candRaw, &s_c[C_GEN], tid);
        for (int a = 0; a < 10 && (nc < KTOP || nc > CAP); ++a) {
            eps = (nc > CAP) ? eps * 0.25f : fminf(eps * 4.f, 1.f);
            nc = collect_direct64(prow, V, MsP * (1.f - eps), candRaw, &s_c[C_GEN], tid);
        }
        if (nc > CAP) nc = CAP;
        find_topk64(candRaw, nc, topP, s_merge, tid);
    }
    if (!okQ) {
        float eps = eps0;
        int nc = collect_direct64(qrow, V, MsQ * (1.f - eps), candRaw, &s_c[C_GEN], tid);
        for (int a = 0; a < 10 && (nc < KTOP || nc > CAP); ++a) {
            eps = (nc > CAP) ? eps * 0.25f : fminf(eps * 4.f, 1.f);
            nc = collect_direct64(qrow, V, MsQ * (1.f - eps), candRaw, &s_c[C_GEN], tid);
        }
        if (nc > CAP) nc = CAP;
        find_topk64(candRaw, nc, topQ, s_merge, tid);
    }
    __syncthreads();

    // ---- union of index sets (wave 0) ----
    if (tid < KTOP) s_union[tid] = topP[tid];
    __syncthreads();
    if (tid < 64) {
        bool freshb = false; uint16_t qi = 0;
        if (tid < KTOP) {
            qi = topQ[tid]; freshb = true;
            for (int j = 0; j < KTOP; ++j) if (topP[j] == qi) freshb = false;
        }
        u64 mb = __ballot(freshb);
        int pos = __popcll(mb & ((1ull << tid) - 1ull));
        if (freshb) s_union[KTOP + pos] = qi;
        if (tid == 0) s_nu = KTOP + __popcll(mb);
    }
    __syncthreads();
    int nu = s_nu;

    // ---- gather union values (index clamp guards pathological fallbacks) ----
    float pv = 0.f, qv = 0.f;
    if (tid < nu) {
        int ui = s_union[tid]; ui = ui < V ? ui : V - 1;
        pv = prow[ui];
        qv = qrow[ui];
    }

    // ---- block-reduce masked sums ----
    float sp = pv, sq = qv;
    for (int off = 32; off; off >>= 1) { sp += __shfl_down(sp, off); sq += __shfl_down(sq, off); }
    if ((tid & 63) == 0) { s_f[w] = sp; s_f[4 + w] = sq; }
    __syncthreads();
    if (tid == 0) {
        float a = 0.f, b = 0.f;
        for (int ww = 0; ww < NTHREADS / 64; ++ww) { a += s_f[ww]; b += s_f[4 + ww]; }
        s_f[0] = a; s_f[4] = b;
    }
    __syncthreads();
    float sump = s_f[0], sumq = s_f[4];
    __syncthreads();

    // ---- JSD over union (identical formula to validated kernels) ----
    float term = 0.f;
    if (tid < nu) {
        float pn = pv / (sump + EPSV);
        float qn = qv / (sumq + EPSV);
        float mn = 0.5f * (pn + qn);
        float ps = pn + EPSV, qs = qn + EPSV, ms = mn + EPSV;
        term = 0.5f * (ps * logf(ps / ms) + qs * logf(qs / ms));
    }
    for (int off = 32; off; off >>= 1) term += __shfl_down(term, off);
    if ((tid & 63) == 0) s_f[w] = term;
    __syncthreads();
    if (tid == 0) {
        float a = 0.f;
        for (int ww = 0; ww < NTHREADS / 64; ++ww) a += s_f[ww];
        out[row] = a;
    }
}

extern "C" void kernel_launch(void* const* d_in, const int* in_sizes, int n_in,
                              void* d_out, int out_size, void* d_ws, size_t ws_size,
                              hipStream_t stream) {
    const float* p = (const float*)d_in[0];
    const float* q = (const float*)d_in[1];
    float* out = (float*)d_out;
    if (out_size <= 0) return;
    int N = out_size;            // B*S rows
    int V = in_sizes[0] / N;     // vocab size
    topk_jsd_kernel<<<dim3(N), dim3(NTHREADS), 0, stream>>>(p, q, out, V);
}